// Round 19
// baseline (62.850 us; speedup 1.0000x reference)
//
#include <hip/hip_runtime.h>
#include <hip/hip_bf16.h>

#define NROWS 8192
#define DIM 512

typedef int   i32x4 __attribute__((ext_vector_type(4)));
typedef int   i32x8 __attribute__((ext_vector_type(8)));
typedef float f32x4 __attribute__((ext_vector_type(4)));

#define FP8_SCALE_1 0x7f7f7f7f   // E8M0 127 = 2^0 in all 4 bytes

__device__ __forceinline__ void gld_lds16(const void* g, void* l) {
  __builtin_amdgcn_global_load_lds(
      (__attribute__((address_space(1))) unsigned int*)(g),
      (__attribute__((address_space(3))) unsigned int*)(l),
      16, 0, 0);
}

// ---------- Phase 1: normalize rows -> fp8 e4m3; diag logits in fp32 ----------
__global__ __launch_bounds__(128) void prep_k(
    const float* __restrict__ q, const float* __restrict__ p,
    unsigned int* __restrict__ qh, unsigned int* __restrict__ ph,
    float* __restrict__ diag) {
  const int i = blockIdx.x;
  const int t = threadIdx.x;
  const int lane = t & 63, wid = t >> 6;
  const float4 qv = ((const float4*)(q + (size_t)i * DIM))[t];
  const float4 pv = ((const float4*)(p + (size_t)i * DIM))[t];
  float ssq = qv.x*qv.x + qv.y*qv.y + qv.z*qv.z + qv.w*qv.w;
  float ssp = pv.x*pv.x + pv.y*pv.y + pv.z*pv.z + pv.w*pv.w;
  float dt  = qv.x*pv.x + qv.y*pv.y + qv.z*pv.z + qv.w*pv.w;
  #pragma unroll
  for (int m = 1; m < 64; m <<= 1) {
    ssq += __shfl_xor(ssq, m, 64);
    ssp += __shfl_xor(ssp, m, 64);
    dt  += __shfl_xor(dt,  m, 64);
  }
  __shared__ float red[3][2];
  if (lane == 0) { red[0][wid] = ssq; red[1][wid] = ssp; red[2][wid] = dt; }
  __syncthreads();
  ssq = red[0][0] + red[0][1];
  ssp = red[1][0] + red[1][1];
  dt  = red[2][0] + red[2][1];
  const float invq = 1.0f / fmaxf(sqrtf(ssq), 1e-8f);
  const float invp = 1.0f / fmaxf(sqrtf(ssp), 1e-8f);
  int rq = 0, rp = 0;
  rq = __builtin_amdgcn_cvt_pk_fp8_f32(qv.x * invq, qv.y * invq, rq, false);
  rq = __builtin_amdgcn_cvt_pk_fp8_f32(qv.z * invq, qv.w * invq, rq, true);
  rp = __builtin_amdgcn_cvt_pk_fp8_f32(pv.x * invp, pv.y * invp, rp, false);
  rp = __builtin_amdgcn_cvt_pk_fp8_f32(pv.z * invp, pv.w * invp, rp, true);
  qh[i * 128 + t] = (unsigned int)rq;
  ph[i * 128 + t] = (unsigned int)rp;
  if (t == 0) diag[i] = dt * invq * invp * 20.0f;
}

// ---------- Phase 2: MX-fp8 GEMM, 128x128 tiles, 2 independent blocks/CU ----------
// 512 persistent blocks (2/CU), 256 thr = 4 waves (2x2), 64x64 out/wave.
// Mechanism (m114): each SIMD hosts 1 wave from each of 2 barrier-independent
// blocks; one block's MFMA burst covers the other's ds_read burst. r10's
// attempt at this regressed because it was FETCH-bound (128MB @ ~2TB/s); the
// L2-resident XCD map removes that: XCD g owns 16 A-panels (1MB) x 32
// B-panels (2MB) = 3MB < 4MB L2. Bijective: rowpanel=(g&3)*16+(j&15),
// colset=(g>>2)*32+(j>>4)*8, j=b>>3; 8 output tiles/block x 4 K-iters.
// Transposed accumulators (r15): acc = mfma(bf, af) -> lane holds row m=l15
// fixed -> row-sum = 16 reg-adds + 2 shfl + 1 predicated psum write.
__device__ __forceinline__ i32x8 rd32(const char* base, int c0, int sw) {
  const i32x4 lo = *(const i32x4*)(base + ((c0     ) ^ sw));
  const i32x4 hi = *(const i32x4*)(base + ((c0 + 16) ^ sw));
  return __builtin_shufflevector(lo, hi, 0, 1, 2, 3, 4, 5, 6, 7);
}
// stage one 128-row x 128B operand slice (4 gld_lds per thread, 256 threads)
__device__ __forceinline__ void stage_op(const char* __restrict__ g, char* dstb,
                                         int rowbase, int tid, int kb) {
  #pragma unroll
  for (int jj = 0; jj < 4; ++jj) {
    const int idx = jj * 256 + tid;
    const int rl = idx >> 3;
    const int scb = ((idx & 7) << 4) ^ ((rl & 7) << 4);
    gld_lds16(g + (size_t)(rowbase + rl) * 512 + kb + scb, dstb + idx * 16);
  }
}

__global__ __launch_bounds__(256, 2) void gemm_lse_k(
    const unsigned int* __restrict__ qh, const unsigned int* __restrict__ ph,
    float* __restrict__ partial) {
  __shared__ __attribute__((aligned(16))) char lds[66560];  // 2x32KB dbuf + 1KB psum
  const int tid = threadIdx.x;
  const int lane = tid & 63, wid = tid >> 6;
  const int wr = wid >> 1, wc = wid & 1;        // 2x2 wave grid
  const int l15 = lane & 15, l4 = lane >> 4;
  const int sw = (l15 & 7) << 4;
  const int c0 = l4 * 32;
  const int b = blockIdx.x;
  const int g = b & 7;                          // XCD (round-robin dispatch)
  const int j = b >> 3;                         // 0..63 within XCD
  const int bm = ((g & 3) * 16 + (j & 15)) * 128;      // A panel (4 blocks share)
  const int colset = (g >> 2) * 32 + (j >> 4) * 8;     // 8 B panels (16 share)
  const char* qh8 = (const char*)qh;
  const char* ph8 = (const char*)ph;
  float* psum = (float*)(lds + 65536);          // [2][128]
  const int aOff = (wr * 64 + l15) * 128;       // + mf*2048
  const int bOff = 16384 + (wc * 64 + l15) * 128;      // + nf*2048

  f32x4 acc[4][4] = {};                         // [nb][am], transposed
  i32x8 af[4], bf[4];

  // Prologue: stage tile0/kt0, drain, barrier.
  stage_op(qh8, lds, bm, tid, 0);
  stage_op(ph8, lds + 16384, colset * 128, tid, 0);
  asm volatile("s_waitcnt vmcnt(0)" ::: "memory");
  __builtin_amdgcn_s_barrier();

  #pragma unroll 1
  for (int it = 0; it < 32; ++it) {
    const char* rb = lds + (it & 1) * 32768;
    char* sb = lds + ((it + 1) & 1) * 32768;
    const int itn = it + 1;
    const int kbn = (itn & 3) * 128;                       // next K-slice bytes
    const int bnn = (colset + ((itn >> 2) & 7)) * 128;     // next B panel rows

    // front-load all 16 ds_read_b128-pairs for this K-iter
    #pragma unroll
    for (int mf = 0; mf < 4; ++mf)
      af[mf] = rd32(rb + aOff + mf * 2048, c0, sw);
    #pragma unroll
    for (int nf = 0; nf < 4; ++nf)
      bf[nf] = rd32(rb + bOff + nf * 2048, c0, sw);
    if (it < 31) {
      stage_op(qh8, sb, bm, tid, kbn);
      stage_op(ph8, sb + 16384, bnn, tid, kbn);
    }
    __builtin_amdgcn_s_setprio(1);
    #pragma unroll
    for (int nf = 0; nf < 4; ++nf)
      #pragma unroll
      for (int mf = 0; mf < 4; ++mf)
        acc[nf][mf] = __builtin_amdgcn_mfma_scale_f32_16x16x128_f8f6f4(
            bf[nf], af[mf], acc[nf][mf], 0, 0, 0, FP8_SCALE_1, 0, FP8_SCALE_1);
    __builtin_amdgcn_s_setprio(0);
    asm volatile("s_waitcnt vmcnt(0)" ::: "memory");  // stages issued early
    __builtin_amdgcn_s_barrier();

    if ((it & 3) == 3) {
      // ---- flush output tile (it>>2): exp(20c-20) + row-sum + store ----
      // Lane holds rows m = wr*64 + am*16 + l15; cols n = wc*64+nb*16+l4*4+r.
      const int colpanel = colset + (it >> 2);
      #pragma unroll
      for (int am = 0; am < 4; ++am) {
        float s = 0.0f;
        #pragma unroll
        for (int nb = 0; nb < 4; ++nb)
          #pragma unroll
          for (int r = 0; r < 4; ++r)
            s += __expf(acc[nb][am][r] * 20.0f - 20.0f);
        s += __shfl_xor(s, 16, 64);
        s += __shfl_xor(s, 32, 64);
        if (l4 == 0)
          psum[wc * 128 + wr * 64 + am * 16 + l15] = s;
      }
      asm volatile("s_waitcnt lgkmcnt(0)" ::: "memory");
      __builtin_amdgcn_s_barrier();
      if (tid < 128)
        partial[(size_t)(bm + tid) * 64 + colpanel] = psum[tid] + psum[128 + tid];
      #pragma unroll
      for (int nb = 0; nb < 4; ++nb)
        #pragma unroll
        for (int am = 0; am < 4; ++am)
          acc[nb][am] = f32x4{0.0f, 0.0f, 0.0f, 0.0f};
    }
  }
}

// ---------- Phase 3a: per-row loss ----------
__global__ __launch_bounds__(256) void rowloss_k(
    const float* __restrict__ partial, const float* __restrict__ diag,
    float* __restrict__ rowloss) {
  const int i = blockIdx.x * 256 + threadIdx.x;
  const float4* pr = (const float4*)(partial + (size_t)i * 64);
  float s = 0.0f;
  #pragma unroll
  for (int c = 0; c < 16; ++c) {
    const float4 v = pr[c];
    s += v.x + v.y + v.z + v.w;
  }
  rowloss[i] = __logf(s) + 20.0f - diag[i];
}

// ---------- Phase 3b: mean ----------
__global__ __launch_bounds__(1024) void final_k(
    const float* __restrict__ rowloss, float* __restrict__ out) {
  const int t = threadIdx.x;
  float s = 0.0f;
  #pragma unroll
  for (int j = 0; j < 8; ++j) s += rowloss[t + j * 1024];
  #pragma unroll
  for (int m = 1; m < 64; m <<= 1) s += __shfl_xor(s, m, 64);
  __shared__ float red[16];
  if ((t & 63) == 0) red[t >> 6] = s;
  __syncthreads();
  if (t == 0) {
    float acc = 0.0f;
    #pragma unroll
    for (int w = 0; w < 16; ++w) acc += red[w];
    out[0] = acc * (1.0f / (float)NROWS);
  }
}

extern "C" void kernel_launch(void* const* d_in, const int* in_sizes, int n_in,
                              void* d_out, int out_size, void* d_ws, size_t ws_size,
                              hipStream_t stream) {
  const float* q = (const float*)d_in[0];
  const float* p = (const float*)d_in[1];
  char* w = (char*)d_ws;
  unsigned int* qh = (unsigned int*)w;                        // 4 MB fp8
  unsigned int* ph = (unsigned int*)(w + 4194304);            // 4 MB fp8
  float* partial    = (float*)(w + 8388608);                  // 2 MB [8192][64]
  float* diag       = (float*)(w + 10485760);                 // 32 KB
  float* rowloss    = (float*)(w + 10485760 + 32768);         // 32 KB
  float* out = (float*)d_out;

  prep_k<<<NROWS, 128, 0, stream>>>(q, p, qh, ph, diag);
  gemm_lse_k<<<512, 256, 0, stream>>>(qh, ph, partial);
  rowloss_k<<<NROWS / 256, 256, 0, stream>>>(partial, diag, rowloss);
  final_k<<<1, 1024, 0, stream>>>(rowloss, out);
}